// Round 1
// baseline (67.604 us; speedup 1.0000x reference)
//
#include <hip/hip_runtime.h>
#include <cstdint>
#include <cstddef>
#include <math.h>

#define B 16
#define S 200
#define D 128
#define VOCAB 100000
#define SCH 8

// K1: attention scores: per block = one (b, chunk of 8 s). 128 threads (one per e-dim).
__global__ __launch_bounds__(128) void k_scores(
    const float* __restrict__ x,
    const float* __restrict__ Wq, const float* __restrict__ bq,
    const float* __restrict__ Wk, const float* __restrict__ bk,
    const float* __restrict__ Wv, const float* __restrict__ bv,
    float* __restrict__ scores)
{
  const int b  = blockIdx.x / (S / SCH);
  const int s0 = (blockIdx.x % (S / SCH)) * SCH;
  const int e  = threadIdx.x;

  __shared__ float lx[SCH][D];
  __shared__ float l0[D];
  __shared__ float sred[2][SCH];

  l0[e] = x[(size_t)b * S * D + e];
  #pragma unroll
  for (int i = 0; i < SCH; i++) lx[i][e] = x[((size_t)b * S + s0 + i) * D + e];
  __syncthreads();

  float q[SCH];
  const float bqe = bq[e];
  #pragma unroll
  for (int i = 0; i < SCH; i++) q[i] = bqe;
  float kk = bk[e];

  for (int d = 0; d < D; d++) {
    const float wq = Wq[d * D + e];
    const float wk = Wk[d * D + e];
    const float x0 = l0[d];
    kk += x0 * wk;
    #pragma unroll
    for (int i = 0; i < SCH; i++) q[i] += lx[i][d] * wq;
  }

  const float wv  = Wv[e];
  const float bv0 = bv[0];
  #pragma unroll
  for (int i = 0; i < SCH; i++) {
    float val = tanhf(q[i] + kk) * wv;
    #pragma unroll
    for (int off = 32; off > 0; off >>= 1) val += __shfl_down(val, off, 64);
    if ((e & 63) == 0) sred[e >> 6][i] = val;
  }
  __syncthreads();
  if (e < SCH) scores[b * S + s0 + e] = sred[0][e] + sred[1][e] + bv0;
}

// K2: softmax over S + c_s; writes cvecT[d*16 + b] (transposed for gemv broadcast).
__global__ __launch_bounds__(256) void k_csum(
    const float* __restrict__ x, const float* __restrict__ scores,
    float* __restrict__ cvecT)
{
  const int b = blockIdx.x;
  const int t = threadIdx.x;
  __shared__ float pr[S];
  __shared__ float red[8];

  float v = (t < S) ? scores[b * S + t] : -INFINITY;
  float m = v;
  #pragma unroll
  for (int off = 32; off > 0; off >>= 1) m = fmaxf(m, __shfl_down(m, off, 64));
  if ((t & 63) == 0) red[t >> 6] = m;
  __syncthreads();
  if (t == 0) red[4] = fmaxf(fmaxf(red[0], red[1]), fmaxf(red[2], red[3]));
  __syncthreads();
  const float mx = red[4];

  float e = (t < S) ? expf(v - mx) : 0.f;
  float s = e;
  #pragma unroll
  for (int off = 32; off > 0; off >>= 1) s += __shfl_down(s, off, 64);
  if ((t & 63) == 0) red[t >> 6] = s;
  __syncthreads();
  if (t == 0) red[5] = red[0] + red[1] + red[2] + red[3];
  __syncthreads();
  const float inv = 1.0f / red[5];
  if (t < S) pr[t] = e * inv;
  __syncthreads();

  if (t < D) {
    float acc = 0.f;
    for (int s2 = 0; s2 < S; s2++) acc += pr[s2] * x[((size_t)b * S + s2) * D + t];
    cvecT[t * B + b]       = x[(size_t)b * S * D + t];  // h_t part (dims 0..127)
    cvecT[(D + t) * B + b] = acc;                        // c_s part (dims 128..255)
  }
}

// K3: p[b][v] = sum_d cvecT[d][b] * Wec[d][v] + bec[v].
// 256 threads: 128 v-slots x 2 d-halves; LDS-staged c, combine halves via LDS.
__global__ __launch_bounds__(256) void k_gemv(
    const float* __restrict__ cvecT, const float* __restrict__ Wec,
    const float* __restrict__ bec, float* __restrict__ out)
{
  __shared__ float cl[2 * D * B];      // 4096 floats
  __shared__ float lred[128 * 17];     // padded to avoid bank conflicts
  const int t = threadIdx.x;
  #pragma unroll
  for (int i = 0; i < 16; i++) cl[t + i * 256] = cvecT[t + i * 256];
  __syncthreads();

  const int vs   = t & 127;
  const int half = t >> 7;
  const int v    = blockIdx.x * 128 + vs;

  float acc[16];
  #pragma unroll
  for (int bb = 0; bb < 16; bb++) acc[bb] = 0.f;

  if (v < VOCAB) {
    const float* wp = Wec + (size_t)half * D * VOCAB + v;
    const float4* c4 = (const float4*)(cl + half * D * B);
    #pragma unroll 4
    for (int d = 0; d < D; d++) {
      const float w = wp[(size_t)d * VOCAB];
      #pragma unroll
      for (int j = 0; j < 4; j++) {
        const float4 c = c4[d * 4 + j];
        acc[4 * j + 0] += c.x * w;
        acc[4 * j + 1] += c.y * w;
        acc[4 * j + 2] += c.z * w;
        acc[4 * j + 3] += c.w * w;
      }
    }
  }

  if (half) {
    #pragma unroll
    for (int bb = 0; bb < 16; bb++) lred[vs * 17 + bb] = acc[bb];
  }
  __syncthreads();
  if (!half && v < VOCAB) {
    const float be = bec[v];
    #pragma unroll
    for (int bb = 0; bb < 16; bb++)
      out[(size_t)bb * VOCAB + v] = acc[bb] + lred[vs * 17 + bb] + be;
  }
}

// K4: scatter -inf for masked ids.
__global__ void k_mask(const int* __restrict__ ids, float* __restrict__ out)
{
  const int i = blockIdx.x * 256 + threadIdx.x;
  if (i >= B * S) return;
  const int id = ids[i];
  if (id > 1) out[(size_t)(i / S) * VOCAB + id] = -INFINITY;
}

// K5: in-place exp + per-(b,chunk) partial sums. No max-subtraction needed
// (logits bounded, |p| < ~10); exp(-inf)=0 handles masked entries.
#define CHUNK 4000
__global__ __launch_bounds__(256) void k_exp(float* __restrict__ out,
                                             float* __restrict__ partial)
{
  const int b = blockIdx.y;
  const int chunk = blockIdx.x;  // 0..24
  const int t = threadIdx.x;
  float s = 0.f;
  const size_t base = (size_t)b * VOCAB + (size_t)chunk * CHUNK;
  for (int i = t; i < CHUNK; i += 256) {
    const float p = out[base + i];
    const float e = expf(p);
    out[base + i] = e;
    s += e;
  }
  #pragma unroll
  for (int off = 32; off > 0; off >>= 1) s += __shfl_down(s, off, 64);
  __shared__ float red[4];
  if ((t & 63) == 0) red[t >> 6] = s;
  __syncthreads();
  if (t == 0) partial[b * 25 + chunk] = red[0] + red[1] + red[2] + red[3];
}

// K5b: combine partials -> 1/sum per batch.
__global__ void k_inv(const float* __restrict__ partial, float* __restrict__ inv)
{
  const int b = threadIdx.x;
  if (b < B) {
    float s = 0.f;
    for (int j = 0; j < 25; j++) s += partial[b * 25 + j];
    inv[b] = 1.0f / s;
  }
}

// K6: scale in place.
__global__ __launch_bounds__(256) void k_norm(float* __restrict__ out,
                                              const float* __restrict__ inv)
{
  const int b = blockIdx.y;
  const int v = blockIdx.x * 256 + threadIdx.x;
  if (v < VOCAB) out[(size_t)b * VOCAB + v] *= inv[b];
}

extern "C" void kernel_launch(void* const* d_in, const int* in_sizes, int n_in,
                              void* d_out, int out_size, void* d_ws, size_t ws_size,
                              hipStream_t stream)
{
  const float* x   = (const float*)d_in[0];
  const int*   ids = (const int*)d_in[1];
  const float* Wq  = (const float*)d_in[2];
  const float* bq  = (const float*)d_in[3];
  const float* Wk  = (const float*)d_in[4];
  const float* bk  = (const float*)d_in[5];
  const float* Wv  = (const float*)d_in[6];
  const float* bv  = (const float*)d_in[7];
  const float* Wec = (const float*)d_in[8];
  const float* bec = (const float*)d_in[9];
  float* out = (float*)d_out;
  float* ws  = (float*)d_ws;

  float* scores  = ws;          // 3200
  float* cvecT   = ws + 3200;   // 4096
  float* partial = ws + 7296;   // 400
  float* inv     = ws + 7696;   // 16

  k_scores<<<dim3(B * (S / SCH)), dim3(128), 0, stream>>>(x, Wq, bq, Wk, bk, Wv, bv, scores);
  k_csum  <<<dim3(B),             dim3(256), 0, stream>>>(x, scores, cvecT);
  k_gemv  <<<dim3((VOCAB + 127) / 128), dim3(256), 0, stream>>>(cvecT, Wec, bec, out);
  k_mask  <<<dim3((B * S + 255) / 256), dim3(256), 0, stream>>>(ids, out);
  k_exp   <<<dim3(25, B),         dim3(256), 0, stream>>>(out, partial);
  k_inv   <<<dim3(1),             dim3(16),  0, stream>>>(partial, inv);
  k_norm  <<<dim3((VOCAB + 255) / 256, B), dim3(256), 0, stream>>>(out, inv);
}